// Round 3
// baseline (564.735 us; speedup 1.0000x reference)
//
#include <hip/hip_runtime.h>
#include <cstddef>

// VOneBlock R3: dn with register-prefetched staging (HBM latency hidden under MFMA),
// persistent zero halo, exact 8 float4/thread staging; gabor with b128 x-window reads.
// ws: [0, 134217728) y2 bf16 [b][h][w][split][256ci]; then gf bf16 fragment-ordered.

#define NSC 128

typedef short s8v __attribute__((ext_vector_type(8)));
typedef float f4v __attribute__((ext_vector_type(4)));

__device__ __forceinline__ short f2bf(float f) {
    unsigned u = __float_as_uint(f);
    unsigned r = (u + 0x7fffu + ((u >> 16) & 1u)) >> 16;
    return (short)r;
}
__device__ __forceinline__ float bf2f(unsigned short s) {
    return __uint_as_float(((unsigned)s) << 16);
}

__global__ __launch_bounds__(256) void prep_g(const float* __restrict__ g,
                                              short* __restrict__ gf) {
    int t = blockIdx.x * 256 + threadIdx.x;      // 589824
    int co = t & 255, ci = (t >> 8) & 255, kxy = t >> 16;
    float v = g[((size_t)co * 256 + ci) * 9 + kxy];
    short hi = f2bf(v);
    short lo = f2bf(v - bf2f((unsigned short)hi));
    int wv = co >> 6, m = (co >> 4) & 3, i = co & 15;
    int cc = ci >> 5, q = (ci >> 3) & 3, j = ci & 7;
    int l = q * 16 + i;
    size_t base = ((((size_t)(kxy * 4 + wv) * 4 + m) * 8 + cc) * 2) * 512 + (size_t)l * 8 + j;
    gf[base] = hi;
    gf[base + 512] = lo;
}

__global__ __launch_bounds__(256) void gabor(const float* __restrict__ x,
                                             const float* __restrict__ wq0,
                                             const float* __restrict__ wq1,
                                             short* __restrict__ y2) {
    __shared__ float xbuf[5][132];
    int oh = blockIdx.x, b = blockIdx.y, c = threadIdx.x;
    for (int i = c; i < 5 * 132; i += 256) (&xbuf[0][0])[i] = 0.f;
    __syncthreads();
    int ihb = oh * 2 - 2;
    for (int i = c; i < 5 * 128; i += 256) {
        int r = i >> 7, col = i & 127;
        int ih = ihb + r;
        if ((unsigned)ih < 128u)
            xbuf[r][col + 2] = x[((size_t)b * 128 + ih) * 128 + col];
    }
    short* yb = y2 + ((size_t)(b * 64 + oh) * 64) * 512 + c;

    if (c < NSC) {                                // simple cells: q0 only
        float w0[25];
#pragma unroll
        for (int i = 0; i < 25; ++i) w0[i] = wq0[c * 25 + i];
        __syncthreads();
        for (int og = 0; og < 16; ++og) {
            int cb = og * 8;
            float q0[4] = {0.f, 0.f, 0.f, 0.f};
#pragma unroll
            for (int ky = 0; ky < 5; ++ky) {
                float xr[12];
                *(float4*)&xr[0] = *(const float4*)&xbuf[ky][cb];
                *(float4*)&xr[4] = *(const float4*)&xbuf[ky][cb + 4];
                *(float4*)&xr[8] = *(const float4*)&xbuf[ky][cb + 8];
#pragma unroll
                for (int j = 0; j < 4; ++j)
#pragma unroll
                    for (int kx = 0; kx < 5; ++kx)
                        q0[j] = fmaf(w0[ky * 5 + kx], xr[2 * j + kx], q0[j]);
            }
#pragma unroll
            for (int j = 0; j < 4; ++j) {
                float v = 25.f * fmaxf(q0[j], 0.f);
                short hi = f2bf(v);
                short lo = f2bf(v - bf2f((unsigned short)hi));
                int ow = og * 4 + j;
                yb[(size_t)ow * 512] = hi;
                yb[(size_t)ow * 512 + 256] = lo;
            }
        }
    } else {                                      // complex cells: q0 & q1
        float w0[25], w1[25];
#pragma unroll
        for (int i = 0; i < 25; ++i) w0[i] = wq0[c * 25 + i];
#pragma unroll
        for (int i = 0; i < 25; ++i) w1[i] = wq1[c * 25 + i];
        __syncthreads();
        for (int og = 0; og < 16; ++og) {
            int cb = og * 8;
            float q0[4] = {0.f, 0.f, 0.f, 0.f}, q1[4] = {0.f, 0.f, 0.f, 0.f};
#pragma unroll
            for (int ky = 0; ky < 5; ++ky) {
                float xr[12];
                *(float4*)&xr[0] = *(const float4*)&xbuf[ky][cb];
                *(float4*)&xr[4] = *(const float4*)&xbuf[ky][cb + 4];
                *(float4*)&xr[8] = *(const float4*)&xbuf[ky][cb + 8];
#pragma unroll
                for (int j = 0; j < 4; ++j)
#pragma unroll
                    for (int kx = 0; kx < 5; ++kx) {
                        q0[j] = fmaf(w0[ky * 5 + kx], xr[2 * j + kx], q0[j]);
                        q1[j] = fmaf(w1[ky * 5 + kx], xr[2 * j + kx], q1[j]);
                    }
            }
#pragma unroll
            for (int j = 0; j < 4; ++j) {
                float v = 25.f * sqrtf(fmaf(q0[j], q0[j], q1[j] * q1[j])) * 0.70710678118654752f;
                short hi = f2bf(v);
                short lo = f2bf(v - bf2f((unsigned short)hi));
                int ow = og * 4 + j;
                yb[(size_t)ow * 512] = hi;
                yb[(size_t)ow * 512 + 256] = lo;
            }
        }
    }
}

__device__ __forceinline__ void dn_load_phase(const short* __restrict__ y2,
                                              int b, int h, int tid, int p,
                                              float4* rh, float4* rl) {
    int ky = p >> 1, half = p & 1;
    int hh = h + ky - 1;
    if ((unsigned)hh < 64u) {
        const float4* rowbase = (const float4*)(y2 + (size_t)((b * 64 + hh) * 64) * 512);
#pragma unroll
        for (int p4 = 0; p4 < 4; ++p4) {
            int i = p4 * 256 + tid;            // 0..1023
            int w = i >> 4, gr = i & 15;
            rh[p4] = rowbase[(size_t)w * 64 + half * 16 + gr];
            rl[p4] = rowbase[(size_t)w * 64 + 32 + half * 16 + gr];
        }
    } else {
#pragma unroll
        for (int p4 = 0; p4 < 4; ++p4) {
            rh[p4] = (float4){0.f, 0.f, 0.f, 0.f};
            rl[p4] = (float4){0.f, 0.f, 0.f, 0.f};
        }
    }
}

// block = (h, b): 256 co x 64 w. 4 waves, each 64co x 64w = 4x4 frags of 16x16.
__global__ __launch_bounds__(256) void dn(const short* __restrict__ y2,
                                          const short* __restrict__ gf,
                                          float* __restrict__ out) {
    __shared__ short bhi[66 * 136];   // row stride 17 granules; rows 0 & 65 = persistent zero halo
    __shared__ short blo[66 * 136];
    int h = blockIdx.x, b = blockIdx.y;
    int tid = threadIdx.x;
    int wv = tid >> 6, l = tid & 63;
    int li = l & 15, lq = l >> 4;

    if (tid < 64) {                   // zero halo once (never rewritten)
        int buf = tid >> 5, gr = tid & 15, wl = ((tid >> 4) & 1) ? 65 : 0;
        short* dst = buf ? blo : bhi;
        *(float4*)&dst[wl * 136 + gr * 8] = (float4){0.f, 0.f, 0.f, 0.f};
    }

    f4v acc[4][4];
#pragma unroll
    for (int m = 0; m < 4; ++m)
#pragma unroll
        for (int n = 0; n < 4; ++n)
            acc[m][n] = (f4v){0.f, 0.f, 0.f, 0.f};

    const s8v* BH = (const s8v*)bhi;
    const s8v* BL = (const s8v*)blo;
    const s8v* GA = (const s8v*)gf;

    float4 rh[4], rl[4];
    dn_load_phase(y2, b, h, tid, 0, rh, rl);

    for (int p = 0; p < 6; ++p) {
        __syncthreads();              // prior compute done reading LDS (and halo init)
#pragma unroll
        for (int p4 = 0; p4 < 4; ++p4) {
            int i = p4 * 256 + tid;
            int wl = (i >> 4) + 1, gr = i & 15;
            *(float4*)&bhi[wl * 136 + gr * 8] = rh[p4];
            *(float4*)&blo[wl * 136 + gr * 8] = rl[p4];
        }
        __syncthreads();
        if (p < 5) dn_load_phase(y2, b, h, tid, p + 1, rh, rl);  // hides under MFMA below

        int ky = p >> 1, half = p & 1;
        for (int kx = 0; kx < 3; ++kx) {
            int kxy = ky * 3 + kx;
#pragma unroll
            for (int cc = 0; cc < 4; ++cc) {
                int ccg = half * 4 + cc;
                s8v Bh[4], Bl[4];
#pragma unroll
                for (int nt = 0; nt < 4; ++nt) {
                    int gidx = (nt * 16 + li + kx) * 17 + cc * 4 + lq;
                    Bh[nt] = BH[gidx];
                    Bl[nt] = BL[gidx];
                }
#pragma unroll
                for (int m = 0; m < 4; ++m) {
                    size_t ab = ((((size_t)(kxy * 4 + wv) * 4 + m) * 8 + ccg) * 2) * 64 + l;
                    s8v Ah = GA[ab];
                    s8v Al = GA[ab + 64];
#pragma unroll
                    for (int nt = 0; nt < 4; ++nt) {
                        acc[m][nt] = __builtin_amdgcn_mfma_f32_16x16x32_bf16(Ah, Bh[nt], acc[m][nt], 0, 0, 0);
                        acc[m][nt] = __builtin_amdgcn_mfma_f32_16x16x32_bf16(Ah, Bl[nt], acc[m][nt], 0, 0, 0);
                        acc[m][nt] = __builtin_amdgcn_mfma_f32_16x16x32_bf16(Al, Bh[nt], acc[m][nt], 0, 0, 0);
                    }
                }
            }
        }
    }

    // epilogue: out = y / under, write NCHW
    const short* nrow = y2 + (size_t)((b * 64 + h) * 64) * 512;
#pragma unroll
    for (int m = 0; m < 4; ++m) {
        int co = wv * 64 + m * 16 + lq * 4;
#pragma unroll
        for (int nt = 0; nt < 4; ++nt) {
            int w = nt * 16 + li;
            const short* np = nrow + (size_t)w * 512 + co;
            ushort4 nh = *(const ushort4*)np;
            ushort4 nl = *(const ushort4*)(np + 256);
            float n0 = bf2f(nh.x) + bf2f(nl.x);
            float n1 = bf2f(nh.y) + bf2f(nl.y);
            float n2 = bf2f(nh.z) + bf2f(nl.z);
            float n3 = bf2f(nh.w) + bf2f(nl.w);
            size_t ob = ((size_t)(b * 256 + co) * 64 + h) * 64 + w;
            out[ob]            = n0 / acc[m][nt][0];
            out[ob + 4096]     = n1 / acc[m][nt][1];
            out[ob + 2 * 4096] = n2 / acc[m][nt][2];
            out[ob + 3 * 4096] = n3 / acc[m][nt][3];
        }
    }
}

extern "C" void kernel_launch(void* const* d_in, const int* in_sizes, int n_in,
                              void* d_out, int out_size, void* d_ws, size_t ws_size,
                              hipStream_t stream) {
    const float* x   = (const float*)d_in[0];
    const float* wq0 = (const float*)d_in[1];
    const float* wq1 = (const float*)d_in[2];
    const float* g   = (const float*)d_in[3];
    float* out = (float*)d_out;
    short* y2 = (short*)d_ws;
    short* gf = y2 + 67108864;

    prep_g<<<2304, 256, 0, stream>>>(g, gf);
    gabor<<<dim3(64, 32), 256, 0, stream>>>(x, wq0, wq1, y2);
    dn<<<dim3(64, 32), 256, 0, stream>>>(y2, gf, out);
}

// Round 4
// 514.569 us; speedup vs baseline: 1.0975x; 1.0975x over previous
//
#include <hip/hip_runtime.h>
#include <cstddef>

// VOneBlock R4: dn processes 2 output rows per block -> each A fragment-pair (from L2)
// feeds 24 MFMAs (2 rows), halving A L2 traffic; 2 parity-indexed LDS row buffers so
// only 1 new row staged per phase after ky=0.
// ws: [0, 134217728) y2 bf16 [b][h][w][split][256ci]; then gf bf16 fragment-ordered.

#define NSC 128

typedef short s8v __attribute__((ext_vector_type(8)));
typedef float f4v __attribute__((ext_vector_type(4)));

__device__ __forceinline__ short f2bf(float f) {
    unsigned u = __float_as_uint(f);
    unsigned r = (u + 0x7fffu + ((u >> 16) & 1u)) >> 16;
    return (short)r;
}
__device__ __forceinline__ float bf2f(unsigned short s) {
    return __uint_as_float(((unsigned)s) << 16);
}

__global__ __launch_bounds__(256) void prep_g(const float* __restrict__ g,
                                              short* __restrict__ gf) {
    int t = blockIdx.x * 256 + threadIdx.x;      // 589824
    int co = t & 255, ci = (t >> 8) & 255, kxy = t >> 16;
    float v = g[((size_t)co * 256 + ci) * 9 + kxy];
    short hi = f2bf(v);
    short lo = f2bf(v - bf2f((unsigned short)hi));
    int wv = co >> 6, m = (co >> 4) & 3, i = co & 15;
    int cc = ci >> 5, q = (ci >> 3) & 3, j = ci & 7;
    int l = q * 16 + i;
    size_t base = ((((size_t)(kxy * 4 + wv) * 4 + m) * 8 + cc) * 2) * 512 + (size_t)l * 8 + j;
    gf[base] = hi;
    gf[base + 512] = lo;
}

__global__ __launch_bounds__(256) void gabor(const float* __restrict__ x,
                                             const float* __restrict__ wq0,
                                             const float* __restrict__ wq1,
                                             short* __restrict__ y2) {
    __shared__ float xbuf[5][132];
    int oh = blockIdx.x, b = blockIdx.y, c = threadIdx.x;
    for (int i = c; i < 5 * 132; i += 256) (&xbuf[0][0])[i] = 0.f;
    __syncthreads();
    int ihb = oh * 2 - 2;
    for (int i = c; i < 5 * 128; i += 256) {
        int r = i >> 7, col = i & 127;
        int ih = ihb + r;
        if ((unsigned)ih < 128u)
            xbuf[r][col + 2] = x[((size_t)b * 128 + ih) * 128 + col];
    }
    short* yb = y2 + ((size_t)(b * 64 + oh) * 64) * 512 + c;

    if (c < NSC) {
        float w0[25];
#pragma unroll
        for (int i = 0; i < 25; ++i) w0[i] = wq0[c * 25 + i];
        __syncthreads();
        for (int og = 0; og < 16; ++og) {
            int cb = og * 8;
            float q0[4] = {0.f, 0.f, 0.f, 0.f};
#pragma unroll
            for (int ky = 0; ky < 5; ++ky) {
                float xr[12];
                *(float4*)&xr[0] = *(const float4*)&xbuf[ky][cb];
                *(float4*)&xr[4] = *(const float4*)&xbuf[ky][cb + 4];
                *(float4*)&xr[8] = *(const float4*)&xbuf[ky][cb + 8];
#pragma unroll
                for (int j = 0; j < 4; ++j)
#pragma unroll
                    for (int kx = 0; kx < 5; ++kx)
                        q0[j] = fmaf(w0[ky * 5 + kx], xr[2 * j + kx], q0[j]);
            }
#pragma unroll
            for (int j = 0; j < 4; ++j) {
                float v = 25.f * fmaxf(q0[j], 0.f);
                short hi = f2bf(v);
                short lo = f2bf(v - bf2f((unsigned short)hi));
                int ow = og * 4 + j;
                yb[(size_t)ow * 512] = hi;
                yb[(size_t)ow * 512 + 256] = lo;
            }
        }
    } else {
        float w0[25], w1[25];
#pragma unroll
        for (int i = 0; i < 25; ++i) w0[i] = wq0[c * 25 + i];
#pragma unroll
        for (int i = 0; i < 25; ++i) w1[i] = wq1[c * 25 + i];
        __syncthreads();
        for (int og = 0; og < 16; ++og) {
            int cb = og * 8;
            float q0[4] = {0.f, 0.f, 0.f, 0.f}, q1[4] = {0.f, 0.f, 0.f, 0.f};
#pragma unroll
            for (int ky = 0; ky < 5; ++ky) {
                float xr[12];
                *(float4*)&xr[0] = *(const float4*)&xbuf[ky][cb];
                *(float4*)&xr[4] = *(const float4*)&xbuf[ky][cb + 4];
                *(float4*)&xr[8] = *(const float4*)&xbuf[ky][cb + 8];
#pragma unroll
                for (int j = 0; j < 4; ++j)
#pragma unroll
                    for (int kx = 0; kx < 5; ++kx) {
                        q0[j] = fmaf(w0[ky * 5 + kx], xr[2 * j + kx], q0[j]);
                        q1[j] = fmaf(w1[ky * 5 + kx], xr[2 * j + kx], q1[j]);
                    }
            }
#pragma unroll
            for (int j = 0; j < 4; ++j) {
                float v = 25.f * sqrtf(fmaf(q0[j], q0[j], q1[j] * q1[j])) * 0.70710678118654752f;
                short hi = f2bf(v);
                short lo = f2bf(v - bf2f((unsigned short)hi));
                int ow = og * 4 + j;
                yb[(size_t)ow * 512] = hi;
                yb[(size_t)ow * 512 + 256] = lo;
            }
        }
    }
}

__device__ __forceinline__ void stage_row(const short* __restrict__ y2,
                                          short* __restrict__ bh,
                                          short* __restrict__ bl,
                                          int b, int r, int half, int tid) {
    if ((unsigned)r < 64u) {
        const float4* rowbase = (const float4*)(y2 + (size_t)((b * 64 + r) * 64) * 512);
#pragma unroll
        for (int p4 = 0; p4 < 4; ++p4) {
            int i = p4 * 256 + tid;
            int w = i >> 4, gr = i & 15;
            float4 vh = rowbase[(size_t)w * 64 + half * 16 + gr];
            float4 vl = rowbase[(size_t)w * 64 + 32 + half * 16 + gr];
            *(float4*)&bh[(w + 1) * 136 + gr * 8] = vh;
            *(float4*)&bl[(w + 1) * 136 + gr * 8] = vl;
        }
    } else {
#pragma unroll
        for (int p4 = 0; p4 < 4; ++p4) {
            int i = p4 * 256 + tid;
            int w = i >> 4, gr = i & 15;
            *(float4*)&bh[(w + 1) * 136 + gr * 8] = (float4){0.f, 0.f, 0.f, 0.f};
            *(float4*)&bl[(w + 1) * 136 + gr * 8] = (float4){0.f, 0.f, 0.f, 0.f};
        }
    }
}

// block = (ht, b): 256 co x 64 w x 2 h-rows. 4 waves, each 64co x 64w x 2h.
__global__ __launch_bounds__(256, 2) void dn(const short* __restrict__ y2,
                                             const short* __restrict__ gf,
                                             float* __restrict__ out) {
    __shared__ short bhi[2][66 * 136];   // row stride 17 granules; rows 0/65 = zero halo
    __shared__ short blo[2][66 * 136];
    int h = blockIdx.x * 2, b = blockIdx.y;
    int tid = threadIdx.x;
    int wv = tid >> 6, l = tid & 63;
    int li = l & 15, lq = l >> 4;

    if (tid < 128) {                      // zero halos in both buffers, once
        int buf = (tid >> 6) & 1, which = (tid >> 5) & 1;
        int row = (tid >> 4) & 1, gr = tid & 15;
        short* dst = which ? blo[buf] : bhi[buf];
        *(float4*)&dst[(row ? 65 : 0) * 136 + gr * 8] = (float4){0.f, 0.f, 0.f, 0.f};
    }

    f4v acc[2][4][4];
#pragma unroll
    for (int hs = 0; hs < 2; ++hs)
#pragma unroll
        for (int m = 0; m < 4; ++m)
#pragma unroll
            for (int n = 0; n < 4; ++n)
                acc[hs][m][n] = (f4v){0.f, 0.f, 0.f, 0.f};

    const s8v* GA = (const s8v*)gf;

    for (int half = 0; half < 2; ++half) {
        for (int ky = 0; ky < 3; ++ky) {
            int r0 = h + ky - 1, r1 = h + ky;   // input rows for outputs h, h+1
            __syncthreads();                     // prior phase done reading LDS
            if (ky == 0)
                stage_row(y2, bhi[r0 & 1], blo[r0 & 1], b, r0, half, tid);
            stage_row(y2, bhi[r1 & 1], blo[r1 & 1], b, r1, half, tid);
            __syncthreads();
            const s8v* BH0 = (const s8v*)bhi[r0 & 1];
            const s8v* BL0 = (const s8v*)blo[r0 & 1];
            const s8v* BH1 = (const s8v*)bhi[r1 & 1];
            const s8v* BL1 = (const s8v*)blo[r1 & 1];

            for (int kx = 0; kx < 3; ++kx) {
                int kxy = ky * 3 + kx;
#pragma unroll
                for (int cc = 0; cc < 4; ++cc) {
                    int ccg = half * 4 + cc;
                    s8v Ah[4], Al[4];
#pragma unroll
                    for (int m = 0; m < 4; ++m) {
                        size_t ab = ((((size_t)(kxy * 4 + wv) * 4 + m) * 8 + ccg) * 2) * 64 + l;
                        Ah[m] = GA[ab];
                        Al[m] = GA[ab + 64];
                    }
#pragma unroll
                    for (int hs = 0; hs < 2; ++hs) {
                        const s8v* BH = hs ? BH1 : BH0;
                        const s8v* BL = hs ? BL1 : BL0;
                        s8v Bh[4], Bl[4];
#pragma unroll
                        for (int nt = 0; nt < 4; ++nt) {
                            int gidx = (nt * 16 + li + kx) * 17 + cc * 4 + lq;
                            Bh[nt] = BH[gidx];
                            Bl[nt] = BL[gidx];
                        }
#pragma unroll
                        for (int m = 0; m < 4; ++m)
#pragma unroll
                            for (int nt = 0; nt < 4; ++nt) {
                                acc[hs][m][nt] = __builtin_amdgcn_mfma_f32_16x16x32_bf16(Ah[m], Bh[nt], acc[hs][m][nt], 0, 0, 0);
                                acc[hs][m][nt] = __builtin_amdgcn_mfma_f32_16x16x32_bf16(Ah[m], Bl[nt], acc[hs][m][nt], 0, 0, 0);
                                acc[hs][m][nt] = __builtin_amdgcn_mfma_f32_16x16x32_bf16(Al[m], Bh[nt], acc[hs][m][nt], 0, 0, 0);
                            }
                    }
                }
            }
        }
    }

    // epilogue: out = y / under, write NCHW for rows h and h+1
#pragma unroll
    for (int hs = 0; hs < 2; ++hs) {
        const short* nrow = y2 + (size_t)((b * 64 + h + hs) * 64) * 512;
#pragma unroll
        for (int m = 0; m < 4; ++m) {
            int co = wv * 64 + m * 16 + lq * 4;
#pragma unroll
            for (int nt = 0; nt < 4; ++nt) {
                int w = nt * 16 + li;
                const short* np = nrow + (size_t)w * 512 + co;
                ushort4 nh = *(const ushort4*)np;
                ushort4 nl = *(const ushort4*)(np + 256);
                float n0 = bf2f(nh.x) + bf2f(nl.x);
                float n1 = bf2f(nh.y) + bf2f(nl.y);
                float n2 = bf2f(nh.z) + bf2f(nl.z);
                float n3 = bf2f(nh.w) + bf2f(nl.w);
                size_t ob = ((size_t)(b * 256 + co) * 64 + (h + hs)) * 64 + w;
                out[ob]            = n0 / acc[hs][m][nt][0];
                out[ob + 4096]     = n1 / acc[hs][m][nt][1];
                out[ob + 2 * 4096] = n2 / acc[hs][m][nt][2];
                out[ob + 3 * 4096] = n3 / acc[hs][m][nt][3];
            }
        }
    }
}

extern "C" void kernel_launch(void* const* d_in, const int* in_sizes, int n_in,
                              void* d_out, int out_size, void* d_ws, size_t ws_size,
                              hipStream_t stream) {
    const float* x   = (const float*)d_in[0];
    const float* wq0 = (const float*)d_in[1];
    const float* wq1 = (const float*)d_in[2];
    const float* g   = (const float*)d_in[3];
    float* out = (float*)d_out;
    short* y2 = (short*)d_ws;
    short* gf = y2 + 67108864;

    prep_g<<<2304, 256, 0, stream>>>(g, gf);
    gabor<<<dim3(64, 32), 256, 0, stream>>>(x, wq0, wq1, y2);
    dn<<<dim3(32, 32), 256, 0, stream>>>(y2, gf, out);
}